// Round 10
// baseline (256.133 us; speedup 1.0000x reference)
//
#include <hip/hip_runtime.h>

#define BB 64
#define SS 256
#define HH 1024
#define EE 256
#define VV 32000

typedef unsigned short u16;
typedef __attribute__((ext_vector_type(4))) unsigned short u16x4;
typedef __attribute__((ext_vector_type(8))) short s16x8;
typedef __attribute__((ext_vector_type(4))) float f32x4;

typedef const void __attribute__((address_space(1)))* gas_p;
typedef void __attribute__((address_space(3)))* las_p;

__device__ __forceinline__ u16 f2bf(float f) {
  unsigned u = __builtin_bit_cast(unsigned, f);
  u += 0x7fffu + ((u >> 16) & 1u);
  return (u16)(u >> 16);
}
__device__ __forceinline__ float bf2f(u16 u) {
  return __builtin_bit_cast(float, ((unsigned)u) << 16);
}
__device__ __forceinline__ void gload16(const void* g, void* l) {
  __builtin_amdgcn_global_load_lds((gas_p)g, (las_p)l, 16, 0, 0);
}
#define MFMA16(a, b, c) __builtin_amdgcn_mfma_f32_16x16x32_bf16(a, b, c, 0, 0, 0)

// ---------------------------------------------------------------------------
// 1) fp32 -> bf16 conversions: enc (reordered m = b*S+s), w2, dec_hs
// ---------------------------------------------------------------------------
__global__ __launch_bounds__(256) void k_convert(const float* __restrict__ enc,
    const float* __restrict__ w2, const float* __restrict__ dec,
    u16* __restrict__ Ap, u16* __restrict__ w2b, u16* __restrict__ hb) {
  int bid = blockIdx.x, t = threadIdx.x;
  const float* src;
  u16* dst;
  if (bid < BB * SS) {
    int b = bid >> 8, s = bid & 255;
    src = enc + (size_t)(s * BB + b) * HH;
    dst = Ap + (size_t)bid * HH;
  } else if (bid < BB * SS + HH) {
    int r = bid - BB * SS;
    src = w2 + (size_t)r * HH;
    dst = w2b + (size_t)r * HH;
  } else {
    int b = bid - (BB * SS + HH);
    src = dec + (size_t)b * HH;
    dst = hb + (size_t)b * HH;
  }
  f32x4 v = *(const f32x4*)(src + t * 4);
  u16x4 o = { f2bf(v[0]), f2bf(v[1]), f2bf(v[2]), f2bf(v[3]) };
  *(u16x4*)(dst + t * 4) = o;
}

// ---------------------------------------------------------------------------
// 2) dbias partials via MFMA: dbp[kc][64][1024] = hb @ w1^T (K-slice kc*128)
// grid (8 nt, 8 kc), 256 thr.
// ---------------------------------------------------------------------------
__global__ __launch_bounds__(256) void k_dbmm(const u16* __restrict__ hb,
    const float* __restrict__ w1, float* __restrict__ dbp) {
  int kc = blockIdx.y;
  int kb = kc * 128;
  int n0 = blockIdx.x * 128;
  __shared__ u16 Ws[2][128 * 32];
  int t = threadIdx.x, lane = t & 63, w = t >> 6;
  int wm = w >> 1, wn = w & 1, l15 = lane & 15, lg = lane >> 4;
  f32x4 acc[2][4] = {};
  int kx = (lg ^ ((l15 >> 1) & 3)) * 8;
  int wrow = t >> 1, wh = t & 1;
  int xr = (wrow >> 1) & 3;
  int s0 = (2 * wh) ^ xr, s1 = (2 * wh + 1) ^ xr;
  const float* gW = w1 + (size_t)(n0 + wrow) * HH + kb + wh * 16;
  const u16* gA = hb + kb + lg * 8;
  f32x4 c0 = *(const f32x4*)(gW);
  f32x4 c1 = *(const f32x4*)(gW + 4);
  f32x4 c2 = *(const f32x4*)(gW + 8);
  f32x4 c3 = *(const f32x4*)(gW + 12);
  s16x8 a0 = *(const s16x8*)(gA + (size_t)(wm * 32 + l15) * HH);
  s16x8 a1 = *(const s16x8*)(gA + (size_t)(wm * 32 + 16 + l15) * HH);
  {
    u16* lw = &Ws[0][wrow * 32];
    u16x4 o0 = { f2bf(c0[0]), f2bf(c0[1]), f2bf(c0[2]), f2bf(c0[3]) };
    u16x4 o1 = { f2bf(c1[0]), f2bf(c1[1]), f2bf(c1[2]), f2bf(c1[3]) };
    u16x4 o2 = { f2bf(c2[0]), f2bf(c2[1]), f2bf(c2[2]), f2bf(c2[3]) };
    u16x4 o3 = { f2bf(c3[0]), f2bf(c3[1]), f2bf(c3[2]), f2bf(c3[3]) };
    *(u16x4*)(lw + s0 * 8) = o0; *(u16x4*)(lw + s0 * 8 + 4) = o1;
    *(u16x4*)(lw + s1 * 8) = o2; *(u16x4*)(lw + s1 * 8 + 4) = o3;
  }
  __syncthreads();
  for (int it = 0; it < 4; ++it) {
    int nlast = (it < 3);
    f32x4 n0v, n1v, n2v, n3v;
    s16x8 an0, an1;
    if (nlast) {
      int k1 = (it + 1) * 32;
      n0v = *(const f32x4*)(gW + k1);
      n1v = *(const f32x4*)(gW + k1 + 4);
      n2v = *(const f32x4*)(gW + k1 + 8);
      n3v = *(const f32x4*)(gW + k1 + 12);
      an0 = *(const s16x8*)(gA + (size_t)(wm * 32 + l15) * HH + k1);
      an1 = *(const s16x8*)(gA + (size_t)(wm * 32 + 16 + l15) * HH + k1);
    }
    const u16* wb = Ws[it & 1];
    s16x8 bfr[4];
#pragma unroll
    for (int ni = 0; ni < 4; ++ni)
      bfr[ni] = *(const s16x8*)&wb[(wn * 64 + ni * 16 + l15) * 32 + kx];
#pragma unroll
    for (int ni = 0; ni < 4; ++ni) {
      acc[0][ni] = MFMA16(a0, bfr[ni], acc[0][ni]);
      acc[1][ni] = MFMA16(a1, bfr[ni], acc[1][ni]);
    }
    if (nlast) {
      u16* lw = &Ws[(it + 1) & 1][wrow * 32];
      u16x4 o0 = { f2bf(n0v[0]), f2bf(n0v[1]), f2bf(n0v[2]), f2bf(n0v[3]) };
      u16x4 o1 = { f2bf(n1v[0]), f2bf(n1v[1]), f2bf(n1v[2]), f2bf(n1v[3]) };
      u16x4 o2 = { f2bf(n2v[0]), f2bf(n2v[1]), f2bf(n2v[2]), f2bf(n2v[3]) };
      u16x4 o3 = { f2bf(n3v[0]), f2bf(n3v[1]), f2bf(n3v[2]), f2bf(n3v[3]) };
      *(u16x4*)(lw + s0 * 8) = o0; *(u16x4*)(lw + s0 * 8 + 4) = o1;
      *(u16x4*)(lw + s1 * 8) = o2; *(u16x4*)(lw + s1 * 8 + 4) = o3;
      a0 = an0; a1 = an1;
    }
    __syncthreads();
  }
  float* Pb = dbp + (size_t)kc * 64 * HH;
#pragma unroll
  for (int mi = 0; mi < 2; ++mi)
#pragma unroll
    for (int ni = 0; ni < 4; ++ni)
#pragma unroll
      for (int r = 0; r < 4; ++r) {
        int m = wm * 32 + mi * 16 + lg * 4 + r;
        int n = n0 + wn * 64 + ni * 16 + l15;
        Pb[(size_t)m * HH + n] = acc[mi][ni][r];
      }
}

// ---------------------------------------------------------------------------
// 3) big fused GEMM (MFMA16): tanh(Ap @ w2b^T + dbias) . vW -> partial scores
// 128x128 tile, BK=64, XCD co-located remap, (row&7) slot-XOR swizzle.
// grid 1024 (1D), 256 thr  [R5-proven variant]
// ---------------------------------------------------------------------------
__global__ __launch_bounds__(256) void k_biggemm(const u16* __restrict__ Ap,
    const u16* __restrict__ Bw, const float* __restrict__ w1b,
    const float* __restrict__ w2bias, const float* __restrict__ dbp,
    const float* __restrict__ vW, float* __restrict__ sp) {
  __shared__ u16 As[128 * 64];
  __shared__ u16 Bs[128 * 64];
  __shared__ float sc[2][128];
  int bid = blockIdx.x;
  int mt = ((bid >> 6) << 3) | (bid & 7);
  int nt = (bid >> 3) & 7;
  int t = threadIdx.x, lane = t & 63, w = t >> 6;
  int wm = w >> 1, wn = w & 1, l15 = lane & 15, lg = lane >> 4;
  int m0 = mt * 128, n0 = nt * 128;
  int b = m0 >> 8;
  f32x4 acc[4][4] = {};
  int srow = w * 32 + (lane >> 3);
  int cswz = ((lane & 7) ^ (lane >> 3)) * 8;
  const u16* gA = Ap + (size_t)(m0 + srow) * HH + cswz;
  const u16* gB = Bw + (size_t)(n0 + srow) * HH + cswz;
  u16* lA = As + w * 32 * 64;
  u16* lB = Bs + w * 32 * 64;
  for (int it = 0; it < 16; ++it) {
    int k0 = it * 64;
#pragma unroll
    for (int i = 0; i < 4; ++i)
      gload16(gA + (size_t)i * 8 * HH + k0, lA + i * 8 * 64);
#pragma unroll
    for (int i = 0; i < 4; ++i)
      gload16(gB + (size_t)i * 8 * HH + k0, lB + i * 8 * 64);
    __syncthreads();
#pragma unroll
    for (int kk = 0; kk < 2; ++kk) {
      s16x8 af[4], bfr[4];
#pragma unroll
      for (int mi = 0; mi < 4; ++mi) {
        int row = wm * 64 + mi * 16 + l15;
        int slot = (kk * 4 + lg) ^ (row & 7);
        af[mi] = *(const s16x8*)&As[row * 64 + slot * 8];
      }
#pragma unroll
      for (int ni = 0; ni < 4; ++ni) {
        int row = wn * 64 + ni * 16 + l15;
        int slot = (kk * 4 + lg) ^ (row & 7);
        bfr[ni] = *(const s16x8*)&Bs[row * 64 + slot * 8];
      }
#pragma unroll
      for (int mi = 0; mi < 4; ++mi)
#pragma unroll
        for (int ni = 0; ni < 4; ++ni)
          acc[mi][ni] = MFMA16(af[mi], bfr[ni], acc[mi][ni]);
    }
    __syncthreads();
  }
  const float* vv = vW + n0;
  float dbs[4];
#pragma unroll
  for (int ni = 0; ni < 4; ++ni) {
    int nl = wn * 64 + ni * 16 + l15;
    int n = n0 + nl;
    float s = w1b[n] + w2bias[n];
#pragma unroll
    for (int p = 0; p < 8; ++p) s += dbp[(size_t)p * 64 * HH + (size_t)b * HH + n];
    dbs[ni] = s;
  }
#pragma unroll
  for (int mi = 0; mi < 4; ++mi) {
#pragma unroll
    for (int r = 0; r < 4; ++r) {
      float p = 0.f;
#pragma unroll
      for (int ni = 0; ni < 4; ++ni) {
        int nl = wn * 64 + ni * 16 + l15;
        p += tanhf(acc[mi][ni][r] + dbs[ni]) * vv[nl];
      }
      p += __shfl_xor(p, 1); p += __shfl_xor(p, 2);
      p += __shfl_xor(p, 4); p += __shfl_xor(p, 8);
      if (l15 == 0) sc[wn][wm * 64 + mi * 16 + lg * 4 + r] = p;
    }
  }
  __syncthreads();
  if (t < 128) sp[(size_t)(m0 + t) * 8 + nt] = sc[0][t] + sc[1][t];
}

// ---------------------------------------------------------------------------
// 4) fused softmax + context partials. grid (8 sc, 64 b), 256 thr.
// ---------------------------------------------------------------------------
__global__ __launch_bounds__(256) void k_ctxsm(const float* __restrict__ sp,
    const float* __restrict__ vb, const u16* __restrict__ Ap,
    float* __restrict__ attn, float* __restrict__ ctxp) {
  int sc = blockIdx.x, b = blockIdx.y, t = threadIdx.x;
  int lane = t & 63, w = t >> 6;
  const float* row = sp + (size_t)(b * SS + t) * 8;
  f32x4 a = *(const f32x4*)row;
  f32x4 c = *(const f32x4*)(row + 4);
  float score = a[0] + a[1] + a[2] + a[3] + c[0] + c[1] + c[2] + c[3] + vb[0];
  __shared__ float rmax[4], rsum[4], at[SS];
  float m = score;
  for (int mk = 1; mk < 64; mk <<= 1) m = fmaxf(m, __shfl_xor(m, mk));
  if (lane == 0) rmax[w] = m;
  __syncthreads();
  m = fmaxf(fmaxf(rmax[0], rmax[1]), fmaxf(rmax[2], rmax[3]));
  float e = expf(score - m);
  float ssum = e;
  for (int mk = 1; mk < 64; mk <<= 1) ssum += __shfl_xor(ssum, mk);
  if (lane == 0) rsum[w] = ssum;
  __syncthreads();
  float tot = rsum[0] + rsum[1] + rsum[2] + rsum[3];
  float av = e / tot;
  at[t] = av;
  if (sc == 0) attn[(size_t)b * SS + t] = av;
  __syncthreads();
  const u16* base = Ap + (size_t)(b * SS + sc * 32) * HH + t * 4;
  float a0 = 0.f, a1 = 0.f, a2 = 0.f, a3 = 0.f;
#pragma unroll 4
  for (int s = 0; s < 32; ++s) {
    u16x4 v = *(const u16x4*)(base + (size_t)s * HH);
    float w_ = at[sc * 32 + s];
    a0 += w_ * bf2f(v[0]); a1 += w_ * bf2f(v[1]);
    a2 += w_ * bf2f(v[2]); a3 += w_ * bf2f(v[3]);
  }
  f32x4 o = { a0, a1, a2, a3 };
  *(f32x4*)&ctxp[(size_t)(b * 8 + sc) * HH + t * 4] = o;
}

// 4b) combine 8 partials -> gin bf16, plus emb gather
__global__ __launch_bounds__(256) void k_ctxcomb(const float* __restrict__ ctxp,
    const int* __restrict__ x, const float* __restrict__ emb,
    u16* __restrict__ gin) {
  int b = blockIdx.x, t = threadIdx.x;
  f32x4 s = {0.f, 0.f, 0.f, 0.f};
#pragma unroll
  for (int p = 0; p < 8; ++p)
    s += *(const f32x4*)&ctxp[(size_t)(b * 8 + p) * HH + t * 4];
  u16x4 o = { f2bf(s[0]), f2bf(s[1]), f2bf(s[2]), f2bf(s[3]) };
  *(u16x4*)(gin + (size_t)b * 1280 + t * 4) = o;
  int xb = x[b];
  gin[(size_t)b * 1280 + HH + t] = f2bf(emb[(size_t)xb * EE + t]);
}

// ---------------------------------------------------------------------------
// 5) GRU GEMM partials. grid (24 nt, 9 slots), 256 thr.
// ---------------------------------------------------------------------------
__global__ __launch_bounds__(256) void k_gru(const u16* __restrict__ gin,
    const u16* __restrict__ hb, const float* __restrict__ Wih,
    const float* __restrict__ Whh, float* __restrict__ P) {
  int y = blockIdx.y;
  int z = (y >= 5);
  const u16* Ab = z ? hb : gin;
  const float* Wf = z ? Whh : Wih;
  int K = z ? HH : (HH + EE);
  int kb = (z ? (y - 5) : y) * 256;
  int n0 = blockIdx.x * 128;
  __shared__ u16 Ws[2][128 * 32];
  int t = threadIdx.x, lane = t & 63, w = t >> 6;
  int wm = w >> 1, wn = w & 1, l15 = lane & 15, lg = lane >> 4;
  f32x4 acc[2][4] = {};
  int kx = (lg ^ ((l15 >> 1) & 3)) * 8;
  int wrow = t >> 1, wh = t & 1;
  int xr = (wrow >> 1) & 3;
  int s0 = (2 * wh) ^ xr, s1 = (2 * wh + 1) ^ xr;
  const float* gW = Wf + (size_t)(n0 + wrow) * K + kb + wh * 16;
  const u16* gA = Ab + kb + lg * 8;
  f32x4 c0 = *(const f32x4*)(gW);
  f32x4 c1 = *(const f32x4*)(gW + 4);
  f32x4 c2 = *(const f32x4*)(gW + 8);
  f32x4 c3 = *(const f32x4*)(gW + 12);
  s16x8 a0 = *(const s16x8*)(gA + (size_t)(wm * 32 + l15) * K);
  s16x8 a1 = *(const s16x8*)(gA + (size_t)(wm * 32 + 16 + l15) * K);
  {
    u16* lw = &Ws[0][wrow * 32];
    u16x4 o0 = { f2bf(c0[0]), f2bf(c0[1]), f2bf(c0[2]), f2bf(c0[3]) };
    u16x4 o1 = { f2bf(c1[0]), f2bf(c1[1]), f2bf(c1[2]), f2bf(c1[3]) };
    u16x4 o2 = { f2bf(c2[0]), f2bf(c2[1]), f2bf(c2[2]), f2bf(c2[3]) };
    u16x4 o3 = { f2bf(c3[0]), f2bf(c3[1]), f2bf(c3[2]), f2bf(c3[3]) };
    *(u16x4*)(lw + s0 * 8) = o0; *(u16x4*)(lw + s0 * 8 + 4) = o1;
    *(u16x4*)(lw + s1 * 8) = o2; *(u16x4*)(lw + s1 * 8 + 4) = o3;
  }
  __syncthreads();
  for (int it = 0; it < 8; ++it) {
    int nlast = (it < 7);
    f32x4 n0v, n1v, n2v, n3v;
    s16x8 an0, an1;
    if (nlast) {
      int k1 = (it + 1) * 32;
      n0v = *(const f32x4*)(gW + k1);
      n1v = *(const f32x4*)(gW + k1 + 4);
      n2v = *(const f32x4*)(gW + k1 + 8);
      n3v = *(const f32x4*)(gW + k1 + 12);
      an0 = *(const s16x8*)(gA + (size_t)(wm * 32 + l15) * K + k1);
      an1 = *(const s16x8*)(gA + (size_t)(wm * 32 + 16 + l15) * K + k1);
    }
    const u16* wb = Ws[it & 1];
    s16x8 bfr[4];
#pragma unroll
    for (int ni = 0; ni < 4; ++ni)
      bfr[ni] = *(const s16x8*)&wb[(wn * 64 + ni * 16 + l15) * 32 + kx];
#pragma unroll
    for (int ni = 0; ni < 4; ++ni) {
      acc[0][ni] = MFMA16(a0, bfr[ni], acc[0][ni]);
      acc[1][ni] = MFMA16(a1, bfr[ni], acc[1][ni]);
    }
    if (nlast) {
      u16* lw = &Ws[(it + 1) & 1][wrow * 32];
      u16x4 o0 = { f2bf(n0v[0]), f2bf(n0v[1]), f2bf(n0v[2]), f2bf(n0v[3]) };
      u16x4 o1 = { f2bf(n1v[0]), f2bf(n1v[1]), f2bf(n1v[2]), f2bf(n1v[3]) };
      u16x4 o2 = { f2bf(n2v[0]), f2bf(n2v[1]), f2bf(n2v[2]), f2bf(n2v[3]) };
      u16x4 o3 = { f2bf(n3v[0]), f2bf(n3v[1]), f2bf(n3v[2]), f2bf(n3v[3]) };
      *(u16x4*)(lw + s0 * 8) = o0; *(u16x4*)(lw + s0 * 8 + 4) = o1;
      *(u16x4*)(lw + s1 * 8) = o2; *(u16x4*)(lw + s1 * 8 + 4) = o3;
      a0 = an0; a1 = an1;
    }
    __syncthreads();
  }
  float* Pb = P + (size_t)y * 64 * 3072;
#pragma unroll
  for (int mi = 0; mi < 2; ++mi)
#pragma unroll
    for (int ni = 0; ni < 4; ++ni)
#pragma unroll
      for (int r = 0; r < 4; ++r) {
        int m = wm * 32 + mi * 16 + lg * 4 + r;
        int n = n0 + wn * 64 + ni * 16 + l15;
        Pb[(size_t)m * 3072 + n] = acc[mi][ni][r];
      }
}

// ---------------------------------------------------------------------------
// 6) GRU gates -> h_new (fp32 to d_out, bf16 to ws)
// ---------------------------------------------------------------------------
__global__ __launch_bounds__(256) void k_gates(const float* __restrict__ P,
    const float* __restrict__ bih, const float* __restrict__ bhh,
    const float* __restrict__ dec, float* __restrict__ hn_out,
    u16* __restrict__ hnb) {
  int b = blockIdx.x, t = threadIdx.x;
#pragma unroll
  for (int j = 0; j < 4; ++j) {
    int h = t + j * 256;
    float gir = 0.f, giz = 0.f, gin_ = 0.f, ghr = 0.f, ghz = 0.f, ghn = 0.f;
#pragma unroll
    for (int y = 0; y < 5; ++y) {
      const float* r = P + (size_t)(y * 64 + b) * 3072;
      gir += r[h]; giz += r[h + 1024]; gin_ += r[h + 2048];
    }
#pragma unroll
    for (int y = 0; y < 4; ++y) {
      const float* r = P + (size_t)((5 + y) * 64 + b) * 3072;
      ghr += r[h]; ghz += r[h + 1024]; ghn += r[h + 2048];
    }
    float rr = 1.f / (1.f + expf(-(gir + bih[h] + ghr + bhh[h])));
    float zz = 1.f / (1.f + expf(-(giz + bih[1024 + h] + ghz + bhh[1024 + h])));
    float nn = tanhf(gin_ + bih[2048 + h] + rr * (ghn + bhh[2048 + h]));
    float hv = dec[(size_t)b * HH + h];
    float hnew = (1.f - zz) * nn + zz * hv;
    hn_out[(size_t)b * HH + h] = hnew;
    hnb[(size_t)b * HH + h] = f2bf(hnew);
  }
}

// ---------------------------------------------------------------------------
// 7) fc_out = h_new @ fc_W^T + fc_b.  N-tile 64 (500 blocks).
// ---------------------------------------------------------------------------
__global__ __launch_bounds__(256) void k_fc(const u16* __restrict__ hnb,
    const float* __restrict__ W, const float* __restrict__ bias,
    float* __restrict__ out) {
  int n0 = blockIdx.x * 64;
  __shared__ u16 Ws[2][64 * 32];
  int t = threadIdx.x, lane = t & 63, w = t >> 6;
  int wm = w >> 1, wn = w & 1, l15 = lane & 15, lg = lane >> 4;
  f32x4 acc[2][2] = {};
  int kx = (lg ^ ((l15 >> 1) & 3)) * 8;
  int wrow = t >> 2;
  int sq = ((t & 3) ^ ((t >> 3) & 3)) * 8;
  const float* gW = W + (size_t)(n0 + wrow) * HH + (t & 3) * 8;
  const u16* gA = hnb + lg * 8;
  f32x4 c0 = *(const f32x4*)(gW);
  f32x4 c1 = *(const f32x4*)(gW + 4);
  s16x8 a0 = *(const s16x8*)(gA + (size_t)(wm * 32 + l15) * HH);
  s16x8 a1 = *(const s16x8*)(gA + (size_t)(wm * 32 + 16 + l15) * HH);
  {
    u16* lw = &Ws[0][wrow * 32 + sq];
    u16x4 o0 = { f2bf(c0[0]), f2bf(c0[1]), f2bf(c0[2]), f2bf(c0[3]) };
    u16x4 o1 = { f2bf(c1[0]), f2bf(c1[1]), f2bf(c1[2]), f2bf(c1[3]) };
    *(u16x4*)(lw) = o0; *(u16x4*)(lw + 4) = o1;
  }
  __syncthreads();
  for (int it = 0; it < 32; ++it) {
    int nlast = (it < 31);
    f32x4 n0v, n1v;
    s16x8 an0, an1;
    if (nlast) {
      int k1 = (it + 1) * 32;
      n0v = *(const f32x4*)(gW + k1);
      n1v = *(const f32x4*)(gW + k1 + 4);
      an0 = *(const s16x8*)(gA + (size_t)(wm * 32 + l15) * HH + k1);
      an1 = *(const s16x8*)(gA + (size_t)(wm * 32 + 16 + l15) * HH + k1);
    }
    const u16* wb = Ws[it & 1];
    s16x8 bfr[2];
#pragma unroll
    for (int ni = 0; ni < 2; ++ni)
      bfr[ni] = *(const s16x8*)&wb[(wn * 32 + ni * 16 + l15) * 32 + kx];
#pragma unroll
    for (int ni = 0; ni < 2; ++ni) {
      acc[0][ni] = MFMA16(a0, bfr[ni], acc[0][ni]);
      acc[1][ni] = MFMA16(a1, bfr[ni], acc[1][ni]);
    }
    if (nlast) {
      u16* lw = &Ws[(it + 1) & 1][wrow * 32 + sq];
      u16x4 o0 = { f2bf(n0v[0]), f2bf(n0v[1]), f2bf(n0v[2]), f2bf(n0v[3]) };
      u16x4 o1 = { f2bf(n1v[0]), f2bf(n1v[1]), f2bf(n1v[2]), f2bf(n1v[3]) };
      *(u16x4*)(lw) = o0; *(u16x4*)(lw + 4) = o1;
      a0 = an0; a1 = an1;
    }
    __syncthreads();
  }
#pragma unroll
  for (int mi = 0; mi < 2; ++mi)
#pragma unroll
    for (int ni = 0; ni < 2; ++ni)
#pragma unroll
      for (int r = 0; r < 4; ++r) {
        int m = wm * 32 + mi * 16 + lg * 4 + r;
        int n = n0 + wn * 32 + ni * 16 + l15;
        out[(size_t)m * VV + n] = acc[mi][ni][r] + bias[n];
      }
}

// ---------------------------------------------------------------------------
extern "C" void kernel_launch(void* const* d_in, const int* in_sizes, int n_in,
                              void* d_out, int out_size, void* d_ws, size_t ws_size,
                              hipStream_t stream) {
  const int*   x      = (const int*)   d_in[0];
  const float* dec    = (const float*) d_in[1];
  const float* enc    = (const float*) d_in[2];
  const float* emb    = (const float*) d_in[3];
  const float* w1     = (const float*) d_in[4];
  const float* w1b    = (const float*) d_in[5];
  const float* w2     = (const float*) d_in[6];
  const float* w2bias = (const float*) d_in[7];
  const float* vW     = (const float*) d_in[8];
  const float* vb     = (const float*) d_in[9];
  const float* Wih    = (const float*) d_in[10];
  const float* Whh    = (const float*) d_in[11];
  const float* bih    = (const float*) d_in[12];
  const float* bhh    = (const float*) d_in[13];
  const float* fcW    = (const float*) d_in[14];
  const float* fcb    = (const float*) d_in[15];
  float* out = (float*)d_out;
  char* ws = (char*)d_ws;
  u16*   Ap    = (u16*)(ws);                 // 33,554,432
  u16*   w2b   = (u16*)(ws + 33554432);      //  2,097,152
  u16*   hb    = (u16*)(ws + 35651584);      //    131,072
  u16*   gin   = (u16*)(ws + 35782656);      //    163,840
  u16*   hnb   = (u16*)(ws + 35946496);      //    131,072
  float* sp    = (float*)(ws + 36339712);    //    524,288
  float* P     = (float*)(ws + 36864000);    //  7,077,888
  // aliases inside P region (all consumed before gru writes P):
  float* dbp   = P;                          //  2 MB: dbias partials [8][64][1024]
  float* ctxp  = P + 524288;                 //  2 MB: context partials [64*8][1024]
  float* hn   = out + 2048000;
  float* attn = out + 2113536;

  k_convert<<<BB * SS + HH + BB, 256, 0, stream>>>(enc, w2, dec, Ap, w2b, hb);
  k_dbmm<<<dim3(8, 8), 256, 0, stream>>>(hb, w1, dbp);
  // --- TIMING PROBE (this round only): biggemm launched 3x. Idempotent
  // (reads constants, writes identical sp). dur_us - 145.9 = 2 x biggemm cost.
  k_biggemm<<<1024, 256, 0, stream>>>(Ap, w2b, w1b, w2bias, dbp, vW, sp);
  k_biggemm<<<1024, 256, 0, stream>>>(Ap, w2b, w1b, w2bias, dbp, vW, sp);
  k_biggemm<<<1024, 256, 0, stream>>>(Ap, w2b, w1b, w2bias, dbp, vW, sp);
  k_ctxsm<<<dim3(8, BB), 256, 0, stream>>>(sp, vb, Ap, attn, ctxp);
  k_ctxcomb<<<BB, 256, 0, stream>>>(ctxp, x, emb, gin);
  k_gru<<<dim3(24, 9), 256, 0, stream>>>(gin, hb, Wih, Whh, P);
  k_gates<<<BB, 256, 0, stream>>>(P, bih, bhh, dec, hn, hnb);
  k_fc<<<500, 256, 0, stream>>>(hnb, fcW, fcb, out);
}

// Round 11
// 130.488 us; speedup vs baseline: 1.9629x; 1.9629x over previous
//
#include <hip/hip_runtime.h>

#define BB 64
#define SS 256
#define HH 1024
#define EE 256
#define VV 32000

typedef unsigned short u16;
typedef __attribute__((ext_vector_type(4))) unsigned short u16x4;
typedef __attribute__((ext_vector_type(8))) short s16x8;
typedef __attribute__((ext_vector_type(4))) float f32x4;

typedef const void __attribute__((address_space(1)))* gas_p;
typedef void __attribute__((address_space(3)))* las_p;

__device__ __forceinline__ u16 f2bf(float f) {
  unsigned u = __builtin_bit_cast(unsigned, f);
  u += 0x7fffu + ((u >> 16) & 1u);
  return (u16)(u >> 16);
}
__device__ __forceinline__ float bf2f(u16 u) {
  return __builtin_bit_cast(float, ((unsigned)u) << 16);
}
// tanh(x) = 1 - 2/(exp(2x)+1); v_exp_f32 + v_rcp_f32, saturates correctly.
__device__ __forceinline__ float ftanh(float x) {
  float e = __expf(2.0f * x);
  float r = __builtin_amdgcn_rcpf(e + 1.0f);
  return fmaf(-2.0f, r, 1.0f);
}
__device__ __forceinline__ float fsig(float x) {
  float e = __expf(-x);
  return __builtin_amdgcn_rcpf(1.0f + e);
}
__device__ __forceinline__ void gload16(const void* g, void* l) {
  __builtin_amdgcn_global_load_lds((gas_p)g, (las_p)l, 16, 0, 0);
}
#define MFMA16(a, b, c) __builtin_amdgcn_mfma_f32_16x16x32_bf16(a, b, c, 0, 0, 0)

// ---------------------------------------------------------------------------
// 1) fp32 -> bf16 conversions: enc (reordered m = b*S+s), w2, dec_hs
// ---------------------------------------------------------------------------
__global__ __launch_bounds__(256) void k_convert(const float* __restrict__ enc,
    const float* __restrict__ w2, const float* __restrict__ dec,
    u16* __restrict__ Ap, u16* __restrict__ w2b, u16* __restrict__ hb) {
  int bid = blockIdx.x, t = threadIdx.x;
  const float* src;
  u16* dst;
  if (bid < BB * SS) {
    int b = bid >> 8, s = bid & 255;
    src = enc + (size_t)(s * BB + b) * HH;
    dst = Ap + (size_t)bid * HH;
  } else if (bid < BB * SS + HH) {
    int r = bid - BB * SS;
    src = w2 + (size_t)r * HH;
    dst = w2b + (size_t)r * HH;
  } else {
    int b = bid - (BB * SS + HH);
    src = dec + (size_t)b * HH;
    dst = hb + (size_t)b * HH;
  }
  f32x4 v = *(const f32x4*)(src + t * 4);
  u16x4 o = { f2bf(v[0]), f2bf(v[1]), f2bf(v[2]), f2bf(v[3]) };
  *(u16x4*)(dst + t * 4) = o;
}

// ---------------------------------------------------------------------------
// 2) dbias partials via MFMA: dbp[kc][64][1024] = hb @ w1^T (K-slice kc*128)
// grid (8 nt, 8 kc), 256 thr.
// ---------------------------------------------------------------------------
__global__ __launch_bounds__(256) void k_dbmm(const u16* __restrict__ hb,
    const float* __restrict__ w1, float* __restrict__ dbp) {
  int kc = blockIdx.y;
  int kb = kc * 128;
  int n0 = blockIdx.x * 128;
  __shared__ u16 Ws[2][128 * 32];
  int t = threadIdx.x, lane = t & 63, w = t >> 6;
  int wm = w >> 1, wn = w & 1, l15 = lane & 15, lg = lane >> 4;
  f32x4 acc[2][4] = {};
  int kx = (lg ^ ((l15 >> 1) & 3)) * 8;
  int wrow = t >> 1, wh = t & 1;
  int xr = (wrow >> 1) & 3;
  int s0 = (2 * wh) ^ xr, s1 = (2 * wh + 1) ^ xr;
  const float* gW = w1 + (size_t)(n0 + wrow) * HH + kb + wh * 16;
  const u16* gA = hb + kb + lg * 8;
  f32x4 c0 = *(const f32x4*)(gW);
  f32x4 c1 = *(const f32x4*)(gW + 4);
  f32x4 c2 = *(const f32x4*)(gW + 8);
  f32x4 c3 = *(const f32x4*)(gW + 12);
  s16x8 a0 = *(const s16x8*)(gA + (size_t)(wm * 32 + l15) * HH);
  s16x8 a1 = *(const s16x8*)(gA + (size_t)(wm * 32 + 16 + l15) * HH);
  {
    u16* lw = &Ws[0][wrow * 32];
    u16x4 o0 = { f2bf(c0[0]), f2bf(c0[1]), f2bf(c0[2]), f2bf(c0[3]) };
    u16x4 o1 = { f2bf(c1[0]), f2bf(c1[1]), f2bf(c1[2]), f2bf(c1[3]) };
    u16x4 o2 = { f2bf(c2[0]), f2bf(c2[1]), f2bf(c2[2]), f2bf(c2[3]) };
    u16x4 o3 = { f2bf(c3[0]), f2bf(c3[1]), f2bf(c3[2]), f2bf(c3[3]) };
    *(u16x4*)(lw + s0 * 8) = o0; *(u16x4*)(lw + s0 * 8 + 4) = o1;
    *(u16x4*)(lw + s1 * 8) = o2; *(u16x4*)(lw + s1 * 8 + 4) = o3;
  }
  __syncthreads();
  for (int it = 0; it < 4; ++it) {
    int nlast = (it < 3);
    f32x4 n0v, n1v, n2v, n3v;
    s16x8 an0, an1;
    if (nlast) {
      int k1 = (it + 1) * 32;
      n0v = *(const f32x4*)(gW + k1);
      n1v = *(const f32x4*)(gW + k1 + 4);
      n2v = *(const f32x4*)(gW + k1 + 8);
      n3v = *(const f32x4*)(gW + k1 + 12);
      an0 = *(const s16x8*)(gA + (size_t)(wm * 32 + l15) * HH + k1);
      an1 = *(const s16x8*)(gA + (size_t)(wm * 32 + 16 + l15) * HH + k1);
    }
    const u16* wb = Ws[it & 1];
    s16x8 bfr[4];
#pragma unroll
    for (int ni = 0; ni < 4; ++ni)
      bfr[ni] = *(const s16x8*)&wb[(wn * 64 + ni * 16 + l15) * 32 + kx];
#pragma unroll
    for (int ni = 0; ni < 4; ++ni) {
      acc[0][ni] = MFMA16(a0, bfr[ni], acc[0][ni]);
      acc[1][ni] = MFMA16(a1, bfr[ni], acc[1][ni]);
    }
    if (nlast) {
      u16* lw = &Ws[(it + 1) & 1][wrow * 32];
      u16x4 o0 = { f2bf(n0v[0]), f2bf(n0v[1]), f2bf(n0v[2]), f2bf(n0v[3]) };
      u16x4 o1 = { f2bf(n1v[0]), f2bf(n1v[1]), f2bf(n1v[2]), f2bf(n1v[3]) };
      u16x4 o2 = { f2bf(n2v[0]), f2bf(n2v[1]), f2bf(n2v[2]), f2bf(n2v[3]) };
      u16x4 o3 = { f2bf(n3v[0]), f2bf(n3v[1]), f2bf(n3v[2]), f2bf(n3v[3]) };
      *(u16x4*)(lw + s0 * 8) = o0; *(u16x4*)(lw + s0 * 8 + 4) = o1;
      *(u16x4*)(lw + s1 * 8) = o2; *(u16x4*)(lw + s1 * 8 + 4) = o3;
      a0 = an0; a1 = an1;
    }
    __syncthreads();
  }
  float* Pb = dbp + (size_t)kc * 64 * HH;
#pragma unroll
  for (int mi = 0; mi < 2; ++mi)
#pragma unroll
    for (int ni = 0; ni < 4; ++ni)
#pragma unroll
      for (int r = 0; r < 4; ++r) {
        int m = wm * 32 + mi * 16 + lg * 4 + r;
        int n = n0 + wn * 64 + ni * 16 + l15;
        Pb[(size_t)m * HH + n] = acc[mi][ni][r];
      }
}

// ---------------------------------------------------------------------------
// 3) big fused GEMM (MFMA16): tanh(Ap @ w2b^T + dbias) . vW -> partial scores
// 128x128 tile, BK=64, XCD co-located remap, (row&7) slot-XOR swizzle.
// Epilogue uses fast tanh (v_exp + v_rcp). grid 1024, 256 thr
// ---------------------------------------------------------------------------
__global__ __launch_bounds__(256) void k_biggemm(const u16* __restrict__ Ap,
    const u16* __restrict__ Bw, const float* __restrict__ w1b,
    const float* __restrict__ w2bias, const float* __restrict__ dbp,
    const float* __restrict__ vW, float* __restrict__ sp) {
  __shared__ u16 As[128 * 64];
  __shared__ u16 Bs[128 * 64];
  __shared__ float sc[2][128];
  int bid = blockIdx.x;
  int mt = ((bid >> 6) << 3) | (bid & 7);
  int nt = (bid >> 3) & 7;
  int t = threadIdx.x, lane = t & 63, w = t >> 6;
  int wm = w >> 1, wn = w & 1, l15 = lane & 15, lg = lane >> 4;
  int m0 = mt * 128, n0 = nt * 128;
  int b = m0 >> 8;
  f32x4 acc[4][4] = {};
  int srow = w * 32 + (lane >> 3);
  int cswz = ((lane & 7) ^ (lane >> 3)) * 8;
  const u16* gA = Ap + (size_t)(m0 + srow) * HH + cswz;
  const u16* gB = Bw + (size_t)(n0 + srow) * HH + cswz;
  u16* lA = As + w * 32 * 64;
  u16* lB = Bs + w * 32 * 64;
  for (int it = 0; it < 16; ++it) {
    int k0 = it * 64;
#pragma unroll
    for (int i = 0; i < 4; ++i)
      gload16(gA + (size_t)i * 8 * HH + k0, lA + i * 8 * 64);
#pragma unroll
    for (int i = 0; i < 4; ++i)
      gload16(gB + (size_t)i * 8 * HH + k0, lB + i * 8 * 64);
    __syncthreads();
#pragma unroll
    for (int kk = 0; kk < 2; ++kk) {
      s16x8 af[4], bfr[4];
#pragma unroll
      for (int mi = 0; mi < 4; ++mi) {
        int row = wm * 64 + mi * 16 + l15;
        int slot = (kk * 4 + lg) ^ (row & 7);
        af[mi] = *(const s16x8*)&As[row * 64 + slot * 8];
      }
#pragma unroll
      for (int ni = 0; ni < 4; ++ni) {
        int row = wn * 64 + ni * 16 + l15;
        int slot = (kk * 4 + lg) ^ (row & 7);
        bfr[ni] = *(const s16x8*)&Bs[row * 64 + slot * 8];
      }
#pragma unroll
      for (int mi = 0; mi < 4; ++mi)
#pragma unroll
        for (int ni = 0; ni < 4; ++ni)
          acc[mi][ni] = MFMA16(af[mi], bfr[ni], acc[mi][ni]);
    }
    __syncthreads();
  }
  const float* vv = vW + n0;
  float dbs[4];
#pragma unroll
  for (int ni = 0; ni < 4; ++ni) {
    int nl = wn * 64 + ni * 16 + l15;
    int n = n0 + nl;
    float s = w1b[n] + w2bias[n];
#pragma unroll
    for (int p = 0; p < 8; ++p) s += dbp[(size_t)p * 64 * HH + (size_t)b * HH + n];
    dbs[ni] = s;
  }
#pragma unroll
  for (int mi = 0; mi < 4; ++mi) {
#pragma unroll
    for (int r = 0; r < 4; ++r) {
      float p = 0.f;
#pragma unroll
      for (int ni = 0; ni < 4; ++ni) {
        int nl = wn * 64 + ni * 16 + l15;
        p += ftanh(acc[mi][ni][r] + dbs[ni]) * vv[nl];
      }
      p += __shfl_xor(p, 1); p += __shfl_xor(p, 2);
      p += __shfl_xor(p, 4); p += __shfl_xor(p, 8);
      if (l15 == 0) sc[wn][wm * 64 + mi * 16 + lg * 4 + r] = p;
    }
  }
  __syncthreads();
  if (t < 128) sp[(size_t)(m0 + t) * 8 + nt] = sc[0][t] + sc[1][t];
}

// ---------------------------------------------------------------------------
// 4) fused softmax + context partials. grid (8 sc, 64 b), 256 thr.
// ---------------------------------------------------------------------------
__global__ __launch_bounds__(256) void k_ctxsm(const float* __restrict__ sp,
    const float* __restrict__ vb, const u16* __restrict__ Ap,
    float* __restrict__ attn, float* __restrict__ ctxp) {
  int sc = blockIdx.x, b = blockIdx.y, t = threadIdx.x;
  int lane = t & 63, w = t >> 6;
  const float* row = sp + (size_t)(b * SS + t) * 8;
  f32x4 a = *(const f32x4*)row;
  f32x4 c = *(const f32x4*)(row + 4);
  float score = a[0] + a[1] + a[2] + a[3] + c[0] + c[1] + c[2] + c[3] + vb[0];
  __shared__ float rmax[4], rsum[4], at[SS];
  float m = score;
  for (int mk = 1; mk < 64; mk <<= 1) m = fmaxf(m, __shfl_xor(m, mk));
  if (lane == 0) rmax[w] = m;
  __syncthreads();
  m = fmaxf(fmaxf(rmax[0], rmax[1]), fmaxf(rmax[2], rmax[3]));
  float e = expf(score - m);
  float ssum = e;
  for (int mk = 1; mk < 64; mk <<= 1) ssum += __shfl_xor(ssum, mk);
  if (lane == 0) rsum[w] = ssum;
  __syncthreads();
  float tot = rsum[0] + rsum[1] + rsum[2] + rsum[3];
  float av = e / tot;
  at[t] = av;
  if (sc == 0) attn[(size_t)b * SS + t] = av;
  __syncthreads();
  const u16* base = Ap + (size_t)(b * SS + sc * 32) * HH + t * 4;
  float a0 = 0.f, a1 = 0.f, a2 = 0.f, a3 = 0.f;
#pragma unroll 4
  for (int s = 0; s < 32; ++s) {
    u16x4 v = *(const u16x4*)(base + (size_t)s * HH);
    float w_ = at[sc * 32 + s];
    a0 += w_ * bf2f(v[0]); a1 += w_ * bf2f(v[1]);
    a2 += w_ * bf2f(v[2]); a3 += w_ * bf2f(v[3]);
  }
  f32x4 o = { a0, a1, a2, a3 };
  *(f32x4*)&ctxp[(size_t)(b * 8 + sc) * HH + t * 4] = o;
}

// 4b) combine 8 partials -> gin bf16, plus emb gather
__global__ __launch_bounds__(256) void k_ctxcomb(const float* __restrict__ ctxp,
    const int* __restrict__ x, const float* __restrict__ emb,
    u16* __restrict__ gin) {
  int b = blockIdx.x, t = threadIdx.x;
  f32x4 s = {0.f, 0.f, 0.f, 0.f};
#pragma unroll
  for (int p = 0; p < 8; ++p)
    s += *(const f32x4*)&ctxp[(size_t)(b * 8 + p) * HH + t * 4];
  u16x4 o = { f2bf(s[0]), f2bf(s[1]), f2bf(s[2]), f2bf(s[3]) };
  *(u16x4*)(gin + (size_t)b * 1280 + t * 4) = o;
  int xb = x[b];
  gin[(size_t)b * 1280 + HH + t] = f2bf(emb[(size_t)xb * EE + t]);
}

// ---------------------------------------------------------------------------
// 5) GRU GEMM partials. grid (24 nt, 9 slots), 256 thr. [R5-proven]
// ---------------------------------------------------------------------------
__global__ __launch_bounds__(256) void k_gru(const u16* __restrict__ gin,
    const u16* __restrict__ hb, const float* __restrict__ Wih,
    const float* __restrict__ Whh, float* __restrict__ P) {
  int y = blockIdx.y;
  int z = (y >= 5);
  const u16* Ab = z ? hb : gin;
  const float* Wf = z ? Whh : Wih;
  int K = z ? HH : (HH + EE);
  int kb = (z ? (y - 5) : y) * 256;
  int n0 = blockIdx.x * 128;
  __shared__ u16 Ws[2][128 * 32];
  int t = threadIdx.x, lane = t & 63, w = t >> 6;
  int wm = w >> 1, wn = w & 1, l15 = lane & 15, lg = lane >> 4;
  f32x4 acc[2][4] = {};
  int kx = (lg ^ ((l15 >> 1) & 3)) * 8;
  int wrow = t >> 1, wh = t & 1;
  int xr = (wrow >> 1) & 3;
  int s0 = (2 * wh) ^ xr, s1 = (2 * wh + 1) ^ xr;
  const float* gW = Wf + (size_t)(n0 + wrow) * K + kb + wh * 16;
  const u16* gA = Ab + kb + lg * 8;
  f32x4 c0 = *(const f32x4*)(gW);
  f32x4 c1 = *(const f32x4*)(gW + 4);
  f32x4 c2 = *(const f32x4*)(gW + 8);
  f32x4 c3 = *(const f32x4*)(gW + 12);
  s16x8 a0 = *(const s16x8*)(gA + (size_t)(wm * 32 + l15) * K);
  s16x8 a1 = *(const s16x8*)(gA + (size_t)(wm * 32 + 16 + l15) * K);
  {
    u16* lw = &Ws[0][wrow * 32];
    u16x4 o0 = { f2bf(c0[0]), f2bf(c0[1]), f2bf(c0[2]), f2bf(c0[3]) };
    u16x4 o1 = { f2bf(c1[0]), f2bf(c1[1]), f2bf(c1[2]), f2bf(c1[3]) };
    u16x4 o2 = { f2bf(c2[0]), f2bf(c2[1]), f2bf(c2[2]), f2bf(c2[3]) };
    u16x4 o3 = { f2bf(c3[0]), f2bf(c3[1]), f2bf(c3[2]), f2bf(c3[3]) };
    *(u16x4*)(lw + s0 * 8) = o0; *(u16x4*)(lw + s0 * 8 + 4) = o1;
    *(u16x4*)(lw + s1 * 8) = o2; *(u16x4*)(lw + s1 * 8 + 4) = o3;
  }
  __syncthreads();
  for (int it = 0; it < 8; ++it) {
    int nlast = (it < 7);
    f32x4 n0v, n1v, n2v, n3v;
    s16x8 an0, an1;
    if (nlast) {
      int k1 = (it + 1) * 32;
      n0v = *(const f32x4*)(gW + k1);
      n1v = *(const f32x4*)(gW + k1 + 4);
      n2v = *(const f32x4*)(gW + k1 + 8);
      n3v = *(const f32x4*)(gW + k1 + 12);
      an0 = *(const s16x8*)(gA + (size_t)(wm * 32 + l15) * K + k1);
      an1 = *(const s16x8*)(gA + (size_t)(wm * 32 + 16 + l15) * K + k1);
    }
    const u16* wb = Ws[it & 1];
    s16x8 bfr[4];
#pragma unroll
    for (int ni = 0; ni < 4; ++ni)
      bfr[ni] = *(const s16x8*)&wb[(wn * 64 + ni * 16 + l15) * 32 + kx];
#pragma unroll
    for (int ni = 0; ni < 4; ++ni) {
      acc[0][ni] = MFMA16(a0, bfr[ni], acc[0][ni]);
      acc[1][ni] = MFMA16(a1, bfr[ni], acc[1][ni]);
    }
    if (nlast) {
      u16* lw = &Ws[(it + 1) & 1][wrow * 32];
      u16x4 o0 = { f2bf(n0v[0]), f2bf(n0v[1]), f2bf(n0v[2]), f2bf(n0v[3]) };
      u16x4 o1 = { f2bf(n1v[0]), f2bf(n1v[1]), f2bf(n1v[2]), f2bf(n1v[3]) };
      u16x4 o2 = { f2bf(n2v[0]), f2bf(n2v[1]), f2bf(n2v[2]), f2bf(n2v[3]) };
      u16x4 o3 = { f2bf(n3v[0]), f2bf(n3v[1]), f2bf(n3v[2]), f2bf(n3v[3]) };
      *(u16x4*)(lw + s0 * 8) = o0; *(u16x4*)(lw + s0 * 8 + 4) = o1;
      *(u16x4*)(lw + s1 * 8) = o2; *(u16x4*)(lw + s1 * 8 + 4) = o3;
      a0 = an0; a1 = an1;
    }
    __syncthreads();
  }
  float* Pb = P + (size_t)y * 64 * 3072;
#pragma unroll
  for (int mi = 0; mi < 2; ++mi)
#pragma unroll
    for (int ni = 0; ni < 4; ++ni)
#pragma unroll
      for (int r = 0; r < 4; ++r) {
        int m = wm * 32 + mi * 16 + lg * 4 + r;
        int n = n0 + wn * 64 + ni * 16 + l15;
        Pb[(size_t)m * 3072 + n] = acc[mi][ni][r];
      }
}

// ---------------------------------------------------------------------------
// 6) GRU gates -> h_new (fp32 to d_out, bf16 to ws)
// ---------------------------------------------------------------------------
__global__ __launch_bounds__(256) void k_gates(const float* __restrict__ P,
    const float* __restrict__ bih, const float* __restrict__ bhh,
    const float* __restrict__ dec, float* __restrict__ hn_out,
    u16* __restrict__ hnb) {
  int b = blockIdx.x, t = threadIdx.x;
#pragma unroll
  for (int j = 0; j < 4; ++j) {
    int h = t + j * 256;
    float gir = 0.f, giz = 0.f, gin_ = 0.f, ghr = 0.f, ghz = 0.f, ghn = 0.f;
#pragma unroll
    for (int y = 0; y < 5; ++y) {
      const float* r = P + (size_t)(y * 64 + b) * 3072;
      gir += r[h]; giz += r[h + 1024]; gin_ += r[h + 2048];
    }
#pragma unroll
    for (int y = 0; y < 4; ++y) {
      const float* r = P + (size_t)((5 + y) * 64 + b) * 3072;
      ghr += r[h]; ghz += r[h + 1024]; ghn += r[h + 2048];
    }
    float rr = fsig(gir + bih[h] + ghr + bhh[h]);
    float zz = fsig(giz + bih[1024 + h] + ghz + bhh[1024 + h]);
    float nn = ftanh(gin_ + bih[2048 + h] + rr * (ghn + bhh[2048 + h]));
    float hv = dec[(size_t)b * HH + h];
    float hnew = (1.f - zz) * nn + zz * hv;
    hn_out[(size_t)b * HH + h] = hnew;
    hnb[(size_t)b * HH + h] = f2bf(hnew);
  }
}

// ---------------------------------------------------------------------------
// 7) fc_out = h_new @ fc_W^T + fc_b.  N-tile 64 (500 blocks), BK=64
// (16 iters: half the barriers, 2x in-flight W bytes for latency hiding).
// ---------------------------------------------------------------------------
__global__ __launch_bounds__(256) void k_fc(const u16* __restrict__ hnb,
    const float* __restrict__ W, const float* __restrict__ bias,
    float* __restrict__ out) {
  int n0 = blockIdx.x * 64;
  __shared__ u16 Ws[2][64 * 64];
  int t = threadIdx.x, lane = t & 63, w = t >> 6;
  int wm = w >> 1, wn = w & 1, l15 = lane & 15, lg = lane >> 4;
  f32x4 acc[2][2] = {};
  // W staging: row = t>>2 (64 rows), seg = t&3 (16 floats = logical slots 2s,2s+1)
  int wrow = t >> 2, wseg = t & 3;
  int sA = ((wseg * 2) ^ (wrow & 7)) * 8;
  int sB = ((wseg * 2 + 1) ^ (wrow & 7)) * 8;
  const float* gW = W + (size_t)(n0 + wrow) * HH + wseg * 16;
  const u16* rA0 = hnb + (size_t)(wm * 32 + l15) * HH + lg * 8;
  const u16* rA1 = hnb + (size_t)(wm * 32 + 16 + l15) * HH + lg * 8;
  f32x4 c0 = *(const f32x4*)(gW);
  f32x4 c1 = *(const f32x4*)(gW + 4);
  f32x4 c2 = *(const f32x4*)(gW + 8);
  f32x4 c3 = *(const f32x4*)(gW + 12);
  s16x8 a00 = *(const s16x8*)(rA0);
  s16x8 a01 = *(const s16x8*)(rA0 + 32);
  s16x8 a10 = *(const s16x8*)(rA1);
  s16x8 a11 = *(const s16x8*)(rA1 + 32);
  {
    u16* lw = &Ws[0][wrow * 64];
    *(u16x4*)(lw + sA) = (u16x4){ f2bf(c0[0]), f2bf(c0[1]), f2bf(c0[2]), f2bf(c0[3]) };
    *(u16x4*)(lw + sA + 4) = (u16x4){ f2bf(c1[0]), f2bf(c1[1]), f2bf(c1[2]), f2bf(c1[3]) };
    *(u16x4*)(lw + sB) = (u16x4){ f2bf(c2[0]), f2bf(c2[1]), f2bf(c2[2]), f2bf(c2[3]) };
    *(u16x4*)(lw + sB + 4) = (u16x4){ f2bf(c3[0]), f2bf(c3[1]), f2bf(c3[2]), f2bf(c3[3]) };
  }
  __syncthreads();
  for (int it = 0; it < 16; ++it) {
    int nlast = (it < 15);
    f32x4 n0v, n1v, n2v, n3v;
    s16x8 b00, b01, b10, b11;
    if (nlast) {
      int k1 = (it + 1) * 64;
      n0v = *(const f32x4*)(gW + k1);
      n1v = *(const f32x4*)(gW + k1 + 4);
      n2v = *(const f32x4*)(gW + k1 + 8);
      n3v = *(const f32x4*)(gW + k1 + 12);
      b00 = *(const s16x8*)(rA0 + k1);
      b01 = *(const s16x8*)(rA0 + k1 + 32);
      b10 = *(const s16x8*)(rA1 + k1);
      b11 = *(const s16x8*)(rA1 + k1 + 32);
    }
    const u16* wb = Ws[it & 1];
#pragma unroll
    for (int kk = 0; kk < 2; ++kk) {
      s16x8 bfr[2];
#pragma unroll
      for (int ni = 0; ni < 2; ++ni) {
        int row = wn * 32 + ni * 16 + l15;
        int slot = (kk * 4 + lg) ^ (row & 7);
        bfr[ni] = *(const s16x8*)&wb[row * 64 + slot * 8];
      }
      s16x8 fa0 = kk ? a01 : a00;
      s16x8 fa1 = kk ? a11 : a10;
#pragma unroll
      for (int ni = 0; ni < 2; ++ni) {
        acc[0][ni] = MFMA16(fa0, bfr[ni], acc[0][ni]);
        acc[1][ni] = MFMA16(fa1, bfr[ni], acc[1][ni]);
      }
    }
    if (nlast) {
      u16* lw = &Ws[(it + 1) & 1][wrow * 64];
      *(u16x4*)(lw + sA) = (u16x4){ f2bf(n0v[0]), f2bf(n0v[1]), f2bf(n0v[2]), f2bf(n0v[3]) };
      *(u16x4*)(lw + sA + 4) = (u16x4){ f2bf(n1v[0]), f2bf(n1v[1]), f2bf(n1v[2]), f2bf(n1v[3]) };
      *(u16x4*)(lw + sB) = (u16x4){ f2bf(n2v[0]), f2bf(n2v[1]), f2bf(n2v[2]), f2bf(n2v[3]) };
      *(u16x4*)(lw + sB + 4) = (u16x4){ f2bf(n3v[0]), f2bf(n3v[1]), f2bf(n3v[2]), f2bf(n3v[3]) };
      a00 = b00; a01 = b01; a10 = b10; a11 = b11;
    }
    __syncthreads();
  }
#pragma unroll
  for (int mi = 0; mi < 2; ++mi)
#pragma unroll
    for (int ni = 0; ni < 2; ++ni)
#pragma unroll
      for (int r = 0; r < 4; ++r) {
        int m = wm * 32 + mi * 16 + lg * 4 + r;
        int n = n0 + wn * 32 + ni * 16 + l15;
        out[(size_t)m * VV + n] = acc[mi][ni][r] + bias[n];
      }
}

// ---------------------------------------------------------------------------
extern "C" void kernel_launch(void* const* d_in, const int* in_sizes, int n_in,
                              void* d_out, int out_size, void* d_ws, size_t ws_size,
                              hipStream_t stream) {
  const int*   x      = (const int*)   d_in[0];
  const float* dec    = (const float*) d_in[1];
  const float* enc    = (const float*) d_in[2];
  const float* emb    = (const float*) d_in[3];
  const float* w1     = (const float*) d_in[4];
  const float* w1b    = (const float*) d_in[5];
  const float* w2     = (const float*) d_in[6];
  const float* w2bias = (const float*) d_in[7];
  const float* vW     = (const float*) d_in[8];
  const float* vb     = (const float*) d_in[9];
  const float* Wih    = (const float*) d_in[10];
  const float* Whh    = (const float*) d_in[11];
  const float* bih    = (const float*) d_in[12];
  const float* bhh    = (const float*) d_in[13];
  const float* fcW    = (const float*) d_in[14];
  const float* fcb    = (const float*) d_in[15];
  float* out = (float*)d_out;
  char* ws = (char*)d_ws;
  u16*   Ap    = (u16*)(ws);                 // 33,554,432
  u16*   w2b   = (u16*)(ws + 33554432);      //  2,097,152
  u16*   hb    = (u16*)(ws + 35651584);      //    131,072
  u16*   gin   = (u16*)(ws + 35782656);      //    163,840
  u16*   hnb   = (u16*)(ws + 35946496);      //    131,072
  float* sp    = (float*)(ws + 36339712);    //    524,288
  float* P     = (float*)(ws + 36864000);    //  7,077,888
  // aliases inside P region (all consumed before gru writes P):
  float* dbp   = P;                          //  2 MB: dbias partials [8][64][1024]
  float* ctxp  = P + 524288;                 //  2 MB: context partials [64*8][1024]
  float* hn   = out + 2048000;
  float* attn = out + 2113536;

  k_convert<<<BB * SS + HH + BB, 256, 0, stream>>>(enc, w2, dec, Ap, w2b, hb);
  k_dbmm<<<dim3(8, 8), 256, 0, stream>>>(hb, w1, dbp);
  k_biggemm<<<1024, 256, 0, stream>>>(Ap, w2b, w1b, w2bias, dbp, vW, sp);
  k_ctxsm<<<dim3(8, BB), 256, 0, stream>>>(sp, vb, Ap, attn, ctxp);
  k_ctxcomb<<<BB, 256, 0, stream>>>(ctxp, x, emb, gin);
  k_gru<<<dim3(24, 9), 256, 0, stream>>>(gin, hb, Wih, Whh, P);
  k_gates<<<BB, 256, 0, stream>>>(P, bih, bhh, dec, hn, hnb);
  k_fc<<<500, 256, 0, stream>>>(hnb, fcW, fcb, out);
}

// Round 12
// 128.017 us; speedup vs baseline: 2.0008x; 1.0193x over previous
//
#include <hip/hip_runtime.h>

#define BB 64
#define SS 256
#define HH 1024
#define EE 256
#define VV 32000

typedef unsigned short u16;
typedef __attribute__((ext_vector_type(4))) unsigned short u16x4;
typedef __attribute__((ext_vector_type(8))) short s16x8;
typedef __attribute__((ext_vector_type(4))) float f32x4;

typedef const void __attribute__((address_space(1)))* gas_p;
typedef void __attribute__((address_space(3)))* las_p;

__device__ __forceinline__ u16 f2bf(float f) {
  unsigned u = __builtin_bit_cast(unsigned, f);
  u += 0x7fffu + ((u >> 16) & 1u);
  return (u16)(u >> 16);
}
__device__ __forceinline__ float bf2f(u16 u) {
  return __builtin_bit_cast(float, ((unsigned)u) << 16);
}
// tanh(x) = 1 - 2/(exp(2x)+1); v_exp_f32 + v_rcp_f32, saturates correctly.
__device__ __forceinline__ float ftanh(float x) {
  float e = __expf(2.0f * x);
  float r = __builtin_amdgcn_rcpf(e + 1.0f);
  return fmaf(-2.0f, r, 1.0f);
}
__device__ __forceinline__ float fsig(float x) {
  float e = __expf(-x);
  return __builtin_amdgcn_rcpf(1.0f + e);
}
__device__ __forceinline__ void gload16(const void* g, void* l) {
  __builtin_amdgcn_global_load_lds((gas_p)g, (las_p)l, 16, 0, 0);
}
#define MFMA16(a, b, c) __builtin_amdgcn_mfma_f32_16x16x32_bf16(a, b, c, 0, 0, 0)

// ---------------------------------------------------------------------------
// 1) fp32 -> bf16 conversions: enc (reordered m = b*S+s), w2, dec_hs
// ---------------------------------------------------------------------------
__global__ __launch_bounds__(256) void k_convert(const float* __restrict__ enc,
    const float* __restrict__ w2, const float* __restrict__ dec,
    u16* __restrict__ Ap, u16* __restrict__ w2b, u16* __restrict__ hb) {
  int bid = blockIdx.x, t = threadIdx.x;
  const float* src;
  u16* dst;
  if (bid < BB * SS) {
    int b = bid >> 8, s = bid & 255;
    src = enc + (size_t)(s * BB + b) * HH;
    dst = Ap + (size_t)bid * HH;
  } else if (bid < BB * SS + HH) {
    int r = bid - BB * SS;
    src = w2 + (size_t)r * HH;
    dst = w2b + (size_t)r * HH;
  } else {
    int b = bid - (BB * SS + HH);
    src = dec + (size_t)b * HH;
    dst = hb + (size_t)b * HH;
  }
  f32x4 v = *(const f32x4*)(src + t * 4);
  u16x4 o = { f2bf(v[0]), f2bf(v[1]), f2bf(v[2]), f2bf(v[3]) };
  *(u16x4*)(dst + t * 4) = o;
}

// ---------------------------------------------------------------------------
// 2) dbias partials via MFMA: dbp[kc][64][1024] = hb @ w1^T (K-slice kc*128)
// grid (8 nt, 8 kc), 256 thr.
// ---------------------------------------------------------------------------
__global__ __launch_bounds__(256) void k_dbmm(const u16* __restrict__ hb,
    const float* __restrict__ w1, float* __restrict__ dbp) {
  int kc = blockIdx.y;
  int kb = kc * 128;
  int n0 = blockIdx.x * 128;
  __shared__ u16 Ws[2][128 * 32];
  int t = threadIdx.x, lane = t & 63, w = t >> 6;
  int wm = w >> 1, wn = w & 1, l15 = lane & 15, lg = lane >> 4;
  f32x4 acc[2][4] = {};
  int kx = (lg ^ ((l15 >> 1) & 3)) * 8;
  int wrow = t >> 1, wh = t & 1;
  int xr = (wrow >> 1) & 3;
  int s0 = (2 * wh) ^ xr, s1 = (2 * wh + 1) ^ xr;
  const float* gW = w1 + (size_t)(n0 + wrow) * HH + kb + wh * 16;
  const u16* gA = hb + kb + lg * 8;
  f32x4 c0 = *(const f32x4*)(gW);
  f32x4 c1 = *(const f32x4*)(gW + 4);
  f32x4 c2 = *(const f32x4*)(gW + 8);
  f32x4 c3 = *(const f32x4*)(gW + 12);
  s16x8 a0 = *(const s16x8*)(gA + (size_t)(wm * 32 + l15) * HH);
  s16x8 a1 = *(const s16x8*)(gA + (size_t)(wm * 32 + 16 + l15) * HH);
  {
    u16* lw = &Ws[0][wrow * 32];
    u16x4 o0 = { f2bf(c0[0]), f2bf(c0[1]), f2bf(c0[2]), f2bf(c0[3]) };
    u16x4 o1 = { f2bf(c1[0]), f2bf(c1[1]), f2bf(c1[2]), f2bf(c1[3]) };
    u16x4 o2 = { f2bf(c2[0]), f2bf(c2[1]), f2bf(c2[2]), f2bf(c2[3]) };
    u16x4 o3 = { f2bf(c3[0]), f2bf(c3[1]), f2bf(c3[2]), f2bf(c3[3]) };
    *(u16x4*)(lw + s0 * 8) = o0; *(u16x4*)(lw + s0 * 8 + 4) = o1;
    *(u16x4*)(lw + s1 * 8) = o2; *(u16x4*)(lw + s1 * 8 + 4) = o3;
  }
  __syncthreads();
  for (int it = 0; it < 4; ++it) {
    int nlast = (it < 3);
    f32x4 n0v, n1v, n2v, n3v;
    s16x8 an0, an1;
    if (nlast) {
      int k1 = (it + 1) * 32;
      n0v = *(const f32x4*)(gW + k1);
      n1v = *(const f32x4*)(gW + k1 + 4);
      n2v = *(const f32x4*)(gW + k1 + 8);
      n3v = *(const f32x4*)(gW + k1 + 12);
      an0 = *(const s16x8*)(gA + (size_t)(wm * 32 + l15) * HH + k1);
      an1 = *(const s16x8*)(gA + (size_t)(wm * 32 + 16 + l15) * HH + k1);
    }
    const u16* wb = Ws[it & 1];
    s16x8 bfr[4];
#pragma unroll
    for (int ni = 0; ni < 4; ++ni)
      bfr[ni] = *(const s16x8*)&wb[(wn * 64 + ni * 16 + l15) * 32 + kx];
#pragma unroll
    for (int ni = 0; ni < 4; ++ni) {
      acc[0][ni] = MFMA16(a0, bfr[ni], acc[0][ni]);
      acc[1][ni] = MFMA16(a1, bfr[ni], acc[1][ni]);
    }
    if (nlast) {
      u16* lw = &Ws[(it + 1) & 1][wrow * 32];
      u16x4 o0 = { f2bf(n0v[0]), f2bf(n0v[1]), f2bf(n0v[2]), f2bf(n0v[3]) };
      u16x4 o1 = { f2bf(n1v[0]), f2bf(n1v[1]), f2bf(n1v[2]), f2bf(n1v[3]) };
      u16x4 o2 = { f2bf(n2v[0]), f2bf(n2v[1]), f2bf(n2v[2]), f2bf(n2v[3]) };
      u16x4 o3 = { f2bf(n3v[0]), f2bf(n3v[1]), f2bf(n3v[2]), f2bf(n3v[3]) };
      *(u16x4*)(lw + s0 * 8) = o0; *(u16x4*)(lw + s0 * 8 + 4) = o1;
      *(u16x4*)(lw + s1 * 8) = o2; *(u16x4*)(lw + s1 * 8 + 4) = o3;
      a0 = an0; a1 = an1;
    }
    __syncthreads();
  }
  float* Pb = dbp + (size_t)kc * 64 * HH;
#pragma unroll
  for (int mi = 0; mi < 2; ++mi)
#pragma unroll
    for (int ni = 0; ni < 4; ++ni)
#pragma unroll
      for (int r = 0; r < 4; ++r) {
        int m = wm * 32 + mi * 16 + lg * 4 + r;
        int n = n0 + wn * 64 + ni * 16 + l15;
        Pb[(size_t)m * HH + n] = acc[mi][ni][r];
      }
}

// ---------------------------------------------------------------------------
// 3) big fused GEMM (MFMA16): tanh(Ap @ w2b^T + dbias) . vW -> partial scores
// 128x128 tile, BK=64, XCD co-located remap, (row&7) slot-XOR swizzle.
// dbias/vW loads hoisted BEFORE K-loop (overlap GEMM); per-wave partials
// written DIRECTLY to sp[m][16] (no sc LDS, no final barrier).
// ---------------------------------------------------------------------------
__global__ __launch_bounds__(256) void k_biggemm(const u16* __restrict__ Ap,
    const u16* __restrict__ Bw, const float* __restrict__ w1b,
    const float* __restrict__ w2bias, const float* __restrict__ dbp,
    const float* __restrict__ vW, float* __restrict__ sp) {
  __shared__ u16 As[128 * 64];
  __shared__ u16 Bs[128 * 64];
  int bid = blockIdx.x;
  int mt = ((bid >> 6) << 3) | (bid & 7);
  int nt = (bid >> 3) & 7;
  int t = threadIdx.x, lane = t & 63, w = t >> 6;
  int wm = w >> 1, wn = w & 1, l15 = lane & 15, lg = lane >> 4;
  int m0 = mt * 128, n0 = nt * 128;
  int b = m0 >> 8;
  f32x4 acc[4][4] = {};
  int srow = w * 32 + (lane >> 3);
  int cswz = ((lane & 7) ^ (lane >> 3)) * 8;
  const u16* gA = Ap + (size_t)(m0 + srow) * HH + cswz;
  const u16* gB = Bw + (size_t)(n0 + srow) * HH + cswz;
  u16* lA = As + w * 32 * 64;
  u16* lB = Bs + w * 32 * 64;
  // hoisted epilogue constants (L2-hot; overlap with GEMM)
  float dbs[4], vvv[4];
#pragma unroll
  for (int ni = 0; ni < 4; ++ni) {
    int nl = wn * 64 + ni * 16 + l15;
    int n = n0 + nl;
    float s = w1b[n] + w2bias[n];
#pragma unroll
    for (int p = 0; p < 8; ++p) s += dbp[(size_t)p * 64 * HH + (size_t)b * HH + n];
    dbs[ni] = s;
    vvv[ni] = vW[n];
  }
  for (int it = 0; it < 16; ++it) {
    int k0 = it * 64;
#pragma unroll
    for (int i = 0; i < 4; ++i)
      gload16(gA + (size_t)i * 8 * HH + k0, lA + i * 8 * 64);
#pragma unroll
    for (int i = 0; i < 4; ++i)
      gload16(gB + (size_t)i * 8 * HH + k0, lB + i * 8 * 64);
    __syncthreads();
#pragma unroll
    for (int kk = 0; kk < 2; ++kk) {
      s16x8 af[4], bfr[4];
#pragma unroll
      for (int mi = 0; mi < 4; ++mi) {
        int row = wm * 64 + mi * 16 + l15;
        int slot = (kk * 4 + lg) ^ (row & 7);
        af[mi] = *(const s16x8*)&As[row * 64 + slot * 8];
      }
#pragma unroll
      for (int ni = 0; ni < 4; ++ni) {
        int row = wn * 64 + ni * 16 + l15;
        int slot = (kk * 4 + lg) ^ (row & 7);
        bfr[ni] = *(const s16x8*)&Bs[row * 64 + slot * 8];
      }
#pragma unroll
      for (int mi = 0; mi < 4; ++mi)
#pragma unroll
        for (int ni = 0; ni < 4; ++ni)
          acc[mi][ni] = MFMA16(af[mi], bfr[ni], acc[mi][ni]);
    }
    __syncthreads();
  }
  // epilogue: tanh + dot(vW) over this wave's 64-col half; 16-lane reduce;
  // lane l15==0 writes partial directly to sp[m][nt*2+wn]
#pragma unroll
  for (int mi = 0; mi < 4; ++mi) {
#pragma unroll
    for (int r = 0; r < 4; ++r) {
      float p = ftanh(acc[mi][0][r] + dbs[0]) * vvv[0]
              + ftanh(acc[mi][1][r] + dbs[1]) * vvv[1]
              + ftanh(acc[mi][2][r] + dbs[2]) * vvv[2]
              + ftanh(acc[mi][3][r] + dbs[3]) * vvv[3];
      p += __shfl_xor(p, 1); p += __shfl_xor(p, 2);
      p += __shfl_xor(p, 4); p += __shfl_xor(p, 8);
      if (l15 == 0) {
        int m = m0 + wm * 64 + mi * 16 + lg * 4 + r;
        sp[(size_t)m * 16 + nt * 2 + wn] = p;
      }
    }
  }
}

// ---------------------------------------------------------------------------
// 4) fused softmax + context partials. grid (8 sc, 64 b), 256 thr.
// Row score = sum of 16 sp partials + vb.
// ---------------------------------------------------------------------------
__global__ __launch_bounds__(256) void k_ctxsm(const float* __restrict__ sp,
    const float* __restrict__ vb, const u16* __restrict__ Ap,
    float* __restrict__ attn, float* __restrict__ ctxp) {
  int sc = blockIdx.x, b = blockIdx.y, t = threadIdx.x;
  int lane = t & 63, w = t >> 6;
  const float* row = sp + (size_t)(b * SS + t) * 16;
  f32x4 a = *(const f32x4*)row;
  f32x4 c = *(const f32x4*)(row + 4);
  f32x4 d = *(const f32x4*)(row + 8);
  f32x4 e4 = *(const f32x4*)(row + 12);
  float score = a[0] + a[1] + a[2] + a[3] + c[0] + c[1] + c[2] + c[3]
              + d[0] + d[1] + d[2] + d[3] + e4[0] + e4[1] + e4[2] + e4[3]
              + vb[0];
  __shared__ float rmax[4], rsum[4], at[SS];
  float m = score;
  for (int mk = 1; mk < 64; mk <<= 1) m = fmaxf(m, __shfl_xor(m, mk));
  if (lane == 0) rmax[w] = m;
  __syncthreads();
  m = fmaxf(fmaxf(rmax[0], rmax[1]), fmaxf(rmax[2], rmax[3]));
  float e = expf(score - m);
  float ssum = e;
  for (int mk = 1; mk < 64; mk <<= 1) ssum += __shfl_xor(ssum, mk);
  if (lane == 0) rsum[w] = ssum;
  __syncthreads();
  float tot = rsum[0] + rsum[1] + rsum[2] + rsum[3];
  float av = e / tot;
  at[t] = av;
  if (sc == 0) attn[(size_t)b * SS + t] = av;
  __syncthreads();
  const u16* base = Ap + (size_t)(b * SS + sc * 32) * HH + t * 4;
  float a0 = 0.f, a1 = 0.f, a2 = 0.f, a3 = 0.f;
#pragma unroll 4
  for (int s = 0; s < 32; ++s) {
    u16x4 v = *(const u16x4*)(base + (size_t)s * HH);
    float w_ = at[sc * 32 + s];
    a0 += w_ * bf2f(v[0]); a1 += w_ * bf2f(v[1]);
    a2 += w_ * bf2f(v[2]); a3 += w_ * bf2f(v[3]);
  }
  f32x4 o = { a0, a1, a2, a3 };
  *(f32x4*)&ctxp[(size_t)(b * 8 + sc) * HH + t * 4] = o;
}

// 4b) combine 8 partials -> gin bf16, plus emb gather
__global__ __launch_bounds__(256) void k_ctxcomb(const float* __restrict__ ctxp,
    const int* __restrict__ x, const float* __restrict__ emb,
    u16* __restrict__ gin) {
  int b = blockIdx.x, t = threadIdx.x;
  f32x4 s = {0.f, 0.f, 0.f, 0.f};
#pragma unroll
  for (int p = 0; p < 8; ++p)
    s += *(const f32x4*)&ctxp[(size_t)(b * 8 + p) * HH + t * 4];
  u16x4 o = { f2bf(s[0]), f2bf(s[1]), f2bf(s[2]), f2bf(s[3]) };
  *(u16x4*)(gin + (size_t)b * 1280 + t * 4) = o;
  int xb = x[b];
  gin[(size_t)b * 1280 + HH + t] = f2bf(emb[(size_t)xb * EE + t]);
}

// ---------------------------------------------------------------------------
// 5) GRU GEMM partials. grid (24 nt, 9 slots), 256 thr. [R5-proven]
// ---------------------------------------------------------------------------
__global__ __launch_bounds__(256) void k_gru(const u16* __restrict__ gin,
    const u16* __restrict__ hb, const float* __restrict__ Wih,
    const float* __restrict__ Whh, float* __restrict__ P) {
  int y = blockIdx.y;
  int z = (y >= 5);
  const u16* Ab = z ? hb : gin;
  const float* Wf = z ? Whh : Wih;
  int K = z ? HH : (HH + EE);
  int kb = (z ? (y - 5) : y) * 256;
  int n0 = blockIdx.x * 128;
  __shared__ u16 Ws[2][128 * 32];
  int t = threadIdx.x, lane = t & 63, w = t >> 6;
  int wm = w >> 1, wn = w & 1, l15 = lane & 15, lg = lane >> 4;
  f32x4 acc[2][4] = {};
  int kx = (lg ^ ((l15 >> 1) & 3)) * 8;
  int wrow = t >> 1, wh = t & 1;
  int xr = (wrow >> 1) & 3;
  int s0 = (2 * wh) ^ xr, s1 = (2 * wh + 1) ^ xr;
  const float* gW = Wf + (size_t)(n0 + wrow) * K + kb + wh * 16;
  const u16* gA = Ab + kb + lg * 8;
  f32x4 c0 = *(const f32x4*)(gW);
  f32x4 c1 = *(const f32x4*)(gW + 4);
  f32x4 c2 = *(const f32x4*)(gW + 8);
  f32x4 c3 = *(const f32x4*)(gW + 12);
  s16x8 a0 = *(const s16x8*)(gA + (size_t)(wm * 32 + l15) * K);
  s16x8 a1 = *(const s16x8*)(gA + (size_t)(wm * 32 + 16 + l15) * K);
  {
    u16* lw = &Ws[0][wrow * 32];
    u16x4 o0 = { f2bf(c0[0]), f2bf(c0[1]), f2bf(c0[2]), f2bf(c0[3]) };
    u16x4 o1 = { f2bf(c1[0]), f2bf(c1[1]), f2bf(c1[2]), f2bf(c1[3]) };
    u16x4 o2 = { f2bf(c2[0]), f2bf(c2[1]), f2bf(c2[2]), f2bf(c2[3]) };
    u16x4 o3 = { f2bf(c3[0]), f2bf(c3[1]), f2bf(c3[2]), f2bf(c3[3]) };
    *(u16x4*)(lw + s0 * 8) = o0; *(u16x4*)(lw + s0 * 8 + 4) = o1;
    *(u16x4*)(lw + s1 * 8) = o2; *(u16x4*)(lw + s1 * 8 + 4) = o3;
  }
  __syncthreads();
  for (int it = 0; it < 8; ++it) {
    int nlast = (it < 7);
    f32x4 n0v, n1v, n2v, n3v;
    s16x8 an0, an1;
    if (nlast) {
      int k1 = (it + 1) * 32;
      n0v = *(const f32x4*)(gW + k1);
      n1v = *(const f32x4*)(gW + k1 + 4);
      n2v = *(const f32x4*)(gW + k1 + 8);
      n3v = *(const f32x4*)(gW + k1 + 12);
      an0 = *(const s16x8*)(gA + (size_t)(wm * 32 + l15) * K + k1);
      an1 = *(const s16x8*)(gA + (size_t)(wm * 32 + 16 + l15) * K + k1);
    }
    const u16* wb = Ws[it & 1];
    s16x8 bfr[4];
#pragma unroll
    for (int ni = 0; ni < 4; ++ni)
      bfr[ni] = *(const s16x8*)&wb[(wn * 64 + ni * 16 + l15) * 32 + kx];
#pragma unroll
    for (int ni = 0; ni < 4; ++ni) {
      acc[0][ni] = MFMA16(a0, bfr[ni], acc[0][ni]);
      acc[1][ni] = MFMA16(a1, bfr[ni], acc[1][ni]);
    }
    if (nlast) {
      u16* lw = &Ws[(it + 1) & 1][wrow * 32];
      u16x4 o0 = { f2bf(n0v[0]), f2bf(n0v[1]), f2bf(n0v[2]), f2bf(n0v[3]) };
      u16x4 o1 = { f2bf(n1v[0]), f2bf(n1v[1]), f2bf(n1v[2]), f2bf(n1v[3]) };
      u16x4 o2 = { f2bf(n2v[0]), f2bf(n2v[1]), f2bf(n2v[2]), f2bf(n2v[3]) };
      u16x4 o3 = { f2bf(n3v[0]), f2bf(n3v[1]), f2bf(n3v[2]), f2bf(n3v[3]) };
      *(u16x4*)(lw + s0 * 8) = o0; *(u16x4*)(lw + s0 * 8 + 4) = o1;
      *(u16x4*)(lw + s1 * 8) = o2; *(u16x4*)(lw + s1 * 8 + 4) = o3;
      a0 = an0; a1 = an1;
    }
    __syncthreads();
  }
  float* Pb = P + (size_t)y * 64 * 3072;
#pragma unroll
  for (int mi = 0; mi < 2; ++mi)
#pragma unroll
    for (int ni = 0; ni < 4; ++ni)
#pragma unroll
      for (int r = 0; r < 4; ++r) {
        int m = wm * 32 + mi * 16 + lg * 4 + r;
        int n = n0 + wn * 64 + ni * 16 + l15;
        Pb[(size_t)m * 3072 + n] = acc[mi][ni][r];
      }
}

// ---------------------------------------------------------------------------
// 6) GRU gates -> h_new (fp32 to d_out, bf16 to ws)
// ---------------------------------------------------------------------------
__global__ __launch_bounds__(256) void k_gates(const float* __restrict__ P,
    const float* __restrict__ bih, const float* __restrict__ bhh,
    const float* __restrict__ dec, float* __restrict__ hn_out,
    u16* __restrict__ hnb) {
  int b = blockIdx.x, t = threadIdx.x;
#pragma unroll
  for (int j = 0; j < 4; ++j) {
    int h = t + j * 256;
    float gir = 0.f, giz = 0.f, gin_ = 0.f, ghr = 0.f, ghz = 0.f, ghn = 0.f;
#pragma unroll
    for (int y = 0; y < 5; ++y) {
      const float* r = P + (size_t)(y * 64 + b) * 3072;
      gir += r[h]; giz += r[h + 1024]; gin_ += r[h + 2048];
    }
#pragma unroll
    for (int y = 0; y < 4; ++y) {
      const float* r = P + (size_t)((5 + y) * 64 + b) * 3072;
      ghr += r[h]; ghz += r[h + 1024]; ghn += r[h + 2048];
    }
    float rr = fsig(gir + bih[h] + ghr + bhh[h]);
    float zz = fsig(giz + bih[1024 + h] + ghz + bhh[1024 + h]);
    float nn = ftanh(gin_ + bih[2048 + h] + rr * (ghn + bhh[2048 + h]));
    float hv = dec[(size_t)b * HH + h];
    float hnew = (1.f - zz) * nn + zz * hv;
    hn_out[(size_t)b * HH + h] = hnew;
    hnb[(size_t)b * HH + h] = f2bf(hnew);
  }
}

// ---------------------------------------------------------------------------
// 7) fc_out = h_new @ fc_W^T + fc_b.  N-tile 64 (500 blocks), BK=64.
// ---------------------------------------------------------------------------
__global__ __launch_bounds__(256) void k_fc(const u16* __restrict__ hnb,
    const float* __restrict__ W, const float* __restrict__ bias,
    float* __restrict__ out) {
  int n0 = blockIdx.x * 64;
  __shared__ u16 Ws[2][64 * 64];
  int t = threadIdx.x, lane = t & 63, w = t >> 6;
  int wm = w >> 1, wn = w & 1, l15 = lane & 15, lg = lane >> 4;
  f32x4 acc[2][2] = {};
  int wrow = t >> 2, wseg = t & 3;
  int sA = ((wseg * 2) ^ (wrow & 7)) * 8;
  int sB = ((wseg * 2 + 1) ^ (wrow & 7)) * 8;
  const float* gW = W + (size_t)(n0 + wrow) * HH + wseg * 16;
  const u16* rA0 = hnb + (size_t)(wm * 32 + l15) * HH + lg * 8;
  const u16* rA1 = hnb + (size_t)(wm * 32 + 16 + l15) * HH + lg * 8;
  f32x4 c0 = *(const f32x4*)(gW);
  f32x4 c1 = *(const f32x4*)(gW + 4);
  f32x4 c2 = *(const f32x4*)(gW + 8);
  f32x4 c3 = *(const f32x4*)(gW + 12);
  s16x8 a00 = *(const s16x8*)(rA0);
  s16x8 a01 = *(const s16x8*)(rA0 + 32);
  s16x8 a10 = *(const s16x8*)(rA1);
  s16x8 a11 = *(const s16x8*)(rA1 + 32);
  {
    u16* lw = &Ws[0][wrow * 64];
    *(u16x4*)(lw + sA) = (u16x4){ f2bf(c0[0]), f2bf(c0[1]), f2bf(c0[2]), f2bf(c0[3]) };
    *(u16x4*)(lw + sA + 4) = (u16x4){ f2bf(c1[0]), f2bf(c1[1]), f2bf(c1[2]), f2bf(c1[3]) };
    *(u16x4*)(lw + sB) = (u16x4){ f2bf(c2[0]), f2bf(c2[1]), f2bf(c2[2]), f2bf(c2[3]) };
    *(u16x4*)(lw + sB + 4) = (u16x4){ f2bf(c3[0]), f2bf(c3[1]), f2bf(c3[2]), f2bf(c3[3]) };
  }
  __syncthreads();
  for (int it = 0; it < 16; ++it) {
    int nlast = (it < 15);
    f32x4 n0v, n1v, n2v, n3v;
    s16x8 b00, b01, b10, b11;
    if (nlast) {
      int k1 = (it + 1) * 64;
      n0v = *(const f32x4*)(gW + k1);
      n1v = *(const f32x4*)(gW + k1 + 4);
      n2v = *(const f32x4*)(gW + k1 + 8);
      n3v = *(const f32x4*)(gW + k1 + 12);
      b00 = *(const s16x8*)(rA0 + k1);
      b01 = *(const s16x8*)(rA0 + k1 + 32);
      b10 = *(const s16x8*)(rA1 + k1);
      b11 = *(const s16x8*)(rA1 + k1 + 32);
    }
    const u16* wb = Ws[it & 1];
#pragma unroll
    for (int kk = 0; kk < 2; ++kk) {
      s16x8 bfr[2];
#pragma unroll
      for (int ni = 0; ni < 2; ++ni) {
        int row = wn * 32 + ni * 16 + l15;
        int slot = (kk * 4 + lg) ^ (row & 7);
        bfr[ni] = *(const s16x8*)&wb[row * 64 + slot * 8];
      }
      s16x8 fa0 = kk ? a01 : a00;
      s16x8 fa1 = kk ? a11 : a10;
#pragma unroll
      for (int ni = 0; ni < 2; ++ni) {
        acc[0][ni] = MFMA16(fa0, bfr[ni], acc[0][ni]);
        acc[1][ni] = MFMA16(fa1, bfr[ni], acc[1][ni]);
      }
    }
    if (nlast) {
      u16* lw = &Ws[(it + 1) & 1][wrow * 64];
      *(u16x4*)(lw + sA) = (u16x4){ f2bf(n0v[0]), f2bf(n0v[1]), f2bf(n0v[2]), f2bf(n0v[3]) };
      *(u16x4*)(lw + sA + 4) = (u16x4){ f2bf(n1v[0]), f2bf(n1v[1]), f2bf(n1v[2]), f2bf(n1v[3]) };
      *(u16x4*)(lw + sB) = (u16x4){ f2bf(n2v[0]), f2bf(n2v[1]), f2bf(n2v[2]), f2bf(n2v[3]) };
      *(u16x4*)(lw + sB + 4) = (u16x4){ f2bf(n3v[0]), f2bf(n3v[1]), f2bf(n3v[2]), f2bf(n3v[3]) };
      a00 = b00; a01 = b01; a10 = b10; a11 = b11;
    }
    __syncthreads();
  }
#pragma unroll
  for (int mi = 0; mi < 2; ++mi)
#pragma unroll
    for (int ni = 0; ni < 2; ++ni)
#pragma unroll
      for (int r = 0; r < 4; ++r) {
        int m = wm * 32 + mi * 16 + lg * 4 + r;
        int n = n0 + wn * 32 + ni * 16 + l15;
        out[(size_t)m * VV + n] = acc[mi][ni][r] + bias[n];
      }
}

// ---------------------------------------------------------------------------
extern "C" void kernel_launch(void* const* d_in, const int* in_sizes, int n_in,
                              void* d_out, int out_size, void* d_ws, size_t ws_size,
                              hipStream_t stream) {
  const int*   x      = (const int*)   d_in[0];
  const float* dec    = (const float*) d_in[1];
  const float* enc    = (const float*) d_in[2];
  const float* emb    = (const float*) d_in[3];
  const float* w1     = (const float*) d_in[4];
  const float* w1b    = (const float*) d_in[5];
  const float* w2     = (const float*) d_in[6];
  const float* w2bias = (const float*) d_in[7];
  const float* vW     = (const float*) d_in[8];
  const float* vb     = (const float*) d_in[9];
  const float* Wih    = (const float*) d_in[10];
  const float* Whh    = (const float*) d_in[11];
  const float* bih    = (const float*) d_in[12];
  const float* bhh    = (const float*) d_in[13];
  const float* fcW    = (const float*) d_in[14];
  const float* fcb    = (const float*) d_in[15];
  float* out = (float*)d_out;
  char* ws = (char*)d_ws;
  u16*   Ap    = (u16*)(ws);                 // 33,554,432
  u16*   w2b   = (u16*)(ws + 33554432);      //  2,097,152
  u16*   hb    = (u16*)(ws + 35651584);      //    131,072
  u16*   gin   = (u16*)(ws + 35782656);      //    163,840
  u16*   hnb   = (u16*)(ws + 35946496);      //    131,072
  float* sp    = (float*)(ws + 36339712);    //  16384*16*4 = 1,048,576
  float* P     = (float*)(ws + 37388288);    //  7,077,888
  // aliases inside P region (all consumed before gru writes P):
  float* dbp   = P;                          //  2 MB: dbias partials [8][64][1024]
  float* ctxp  = P + 524288;                 //  2 MB: context partials [64*8][1024]
  float* hn   = out + 2048000;
  float* attn = out + 2113536;

  k_convert<<<BB * SS + HH + BB, 256, 0, stream>>>(enc, w2, dec, Ap, w2b, hb);
  k_dbmm<<<dim3(8, 8), 256, 0, stream>>>(hb, w1, dbp);
  k_biggemm<<<1024, 256, 0, stream>>>(Ap, w2b, w1b, w2bias, dbp, vW, sp);
  k_ctxsm<<<dim3(8, BB), 256, 0, stream>>>(sp, vb, Ap, attn, ctxp);
  k_ctxcomb<<<BB, 256, 0, stream>>>(ctxp, x, emb, gin);
  k_gru<<<dim3(24, 9), 256, 0, stream>>>(gin, hb, Wih, Whh, P);
  k_gates<<<BB, 256, 0, stream>>>(P, bih, bhh, dec, hn, hnb);
  k_fc<<<500, 256, 0, stream>>>(hnb, fcW, fcb, out);
}